// Round 1
// baseline (489.169 us; speedup 1.0000x reference)
//
#include <hip/hip_runtime.h>
#include <hip/hip_bf16.h>

#define DFEAT 128

typedef short bf16x8 __attribute__((ext_vector_type(8)));
typedef float f32x4  __attribute__((ext_vector_type(4)));
typedef unsigned short u16x8 __attribute__((ext_vector_type(8)));

__device__ __forceinline__ unsigned bf16r(float f) {
    unsigned u = __float_as_uint(f);
    u += 0x7fffu + ((u >> 16) & 1u);   // round-to-nearest-even
    return u >> 16;
}
__device__ __forceinline__ unsigned pack_bf16(float lo, float hi) {
    return bf16r(lo) | (bf16r(hi) << 16);
}
__device__ __forceinline__ float blo(unsigned v) { return __uint_as_float(v << 16); }
__device__ __forceinline__ float bhi(unsigned v) { return __uint_as_float(v & 0xffff0000u); }
__device__ __forceinline__ float f16w(unsigned cw) {
    unsigned short wb = (unsigned short)(cw >> 16);
    _Float16 hf; __builtin_memcpy(&hf, &wb, 2);
    return (float)hf;
}

// Chebyshev algebra folded into weights (fp32, at prep):
//   out = h@W0 + Tx1@W1 + (2P - h)@W2,  P = L_hat @ Tx1
//       = h@(W0 - W2) + Tx1@W1 + P@(2*W2)
// -> both props are identical pure gathers (no subtract, no alpha).

// ---------------- conv (FIRST): zero deg8 + x->bf16 pack + W->folded transposed bf16 ----------------
__global__ void conv_kernel(const float2* __restrict__ x, unsigned* __restrict__ xb, int npk,
                            const float* __restrict__ W1, const float* __restrict__ W2,
                            const float* __restrict__ W3, unsigned short* __restrict__ Wt,
                            int* __restrict__ deg8, int N) {
    int id = blockIdx.x * blockDim.x + threadIdx.x;
    int gstride = gridDim.x * blockDim.x;
    for (int i = id; i < 8 * N; i += gstride) deg8[i] = 0;
    if (id < npk) {
        float2 v = x[id];
        xb[id] = pack_bf16(v.x, v.y);
        return;
    }
    int id2 = id - npk;
    const int PER = 3 * DFEAT * DFEAT;
    if (id2 < 3 * PER) {
        int layer = id2 / PER;
        int rem = id2 - layer * PER;
        const float* W = (layer == 0) ? W1 : ((layer == 1) ? W2 : W3);
        int seg = rem >> 14;
        int k   = (rem >> 7) & 127;
        int nn  = rem & 127;
        float w = W[rem];
        if (seg == 0) w -= W[rem + 2 * DFEAT * DFEAT];   // W0' = W0 - W2
        else if (seg == 2) w *= 2.f;                      // W2' = 2*W2
        Wt[layer * PER + (seg << 14) + (nn << 7) + k] = (unsigned short)bf16r(w);
    }
}

// ---------------- degree count (XCD-privatized, fire-and-forget atomics) ----------------
__global__ void deg_kernel(const int* __restrict__ ei, int* __restrict__ deg8, int E, int N) {
    int e = blockIdx.x * blockDim.x + threadIdx.x;
    if (e < E) {
        int r = ei[e];
        int c = ei[E + e];
        if (r != c) atomicAdd(&deg8[(blockIdx.x & 7) * N + r], 1);
    }
}

// ---------------- scan stage 1: partition prefix -> poff, totals -> dinv, block scan ----------------
__global__ __launch_bounds__(1024) void scan1_kernel(const int* __restrict__ deg8,
                                                     int* __restrict__ poff,
                                                     int* __restrict__ row_ptr,
                                                     int* __restrict__ bsum,
                                                     float* __restrict__ dinv, int n) {
    __shared__ int wsums[16];
    int t = threadIdx.x;
    int idx = blockIdx.x * 1024 + t;
    int tot = 0;
    if (idx < n) {
        int run = 0;
        #pragma unroll
        for (int p = 0; p < 8; ++p) {
            int d = deg8[p * n + idx];
            poff[p * n + idx] = run;   // partition start within row; doubles as fill cursor
            run += d;
        }
        tot = run;
        dinv[idx] = (tot > 0) ? rsqrtf((float)tot) : 0.f;
    }
    int vi = tot;
    #pragma unroll
    for (int off = 1; off < 64; off <<= 1) {
        int x = __shfl_up(vi, off);
        if ((t & 63) >= off) vi += x;
    }
    if ((t & 63) == 63) wsums[t >> 6] = vi;
    __syncthreads();
    if (t < 16) {
        int s = wsums[t];
        int si = s;
        #pragma unroll
        for (int off = 1; off < 16; off <<= 1) {
            int x = __shfl_up(si, off);
            if (t >= off) si += x;
        }
        wsums[t] = si - s;
        if (t == 15) bsum[blockIdx.x] = si;   // block total
    }
    __syncthreads();
    if (idx < n) row_ptr[idx + 1] = wsums[t >> 6] + vi;
}

// ---------------- scan stage 2+3 merged: each block reduces its bsum prefix itself ----------------
__global__ __launch_bounds__(1024) void scan3_kernel(int* __restrict__ row_ptr,
                                                     const int* __restrict__ bsum, int n) {
    __shared__ int soff;
    int t = threadIdx.x;
    if (t < 64) {
        int v = 0;
        for (int k = t; k < (int)blockIdx.x; k += 64) v += bsum[k];
        #pragma unroll
        for (int off = 32; off > 0; off >>= 1) v += __shfl_down(v, off);
        if (t == 0) soff = v;
    }
    __syncthreads();
    int idx = blockIdx.x * 1024 + t;
    if (idx == 0) row_ptr[0] = 0;
    if (idx < n) row_ptr[idx + 1] += soff;
}

// ---------------- CSR fill: packed (col:u16 | w:f16); poff doubles as cursor ----------------
__global__ void fill_kernel(const int* __restrict__ ei, const int* __restrict__ row_ptr,
                            int* __restrict__ poff, const float* __restrict__ dinv,
                            unsigned* __restrict__ e_cw, int E, int N) {
    int e = blockIdx.x * blockDim.x + threadIdx.x;
    if (e < E) {
        int r = ei[e];
        int c = ei[E + e];
        if (r != c) {
            int p = blockIdx.x & 7;
            int k = atomicAdd(&poff[p * N + r], 1);   // cursor = partition base + count
            int pos = row_ptr[r] + k;
            float w = -dinv[r] * dinv[c];
            _Float16 hf = (_Float16)w;
            unsigned short wb;
            __builtin_memcpy(&wb, &hf, 2);
            e_cw[pos] = (unsigned)c | ((unsigned)wb << 16);
        }
    }
}

// ---------------- sparse prop (pure gather: hout = L_hat @ hin) ----------------
// 1 wave per node; 2 edges per wave via half-wave split: lane = (h = lane>>5
// edge parity, s = lane&31 8B segment -> features 4s..4s+3). Metadata via
// wave-uniform scalar loads + cndmask select; 12-pair phases -> 6 KB in
// flight per wave. Cross-half shfl_xor reduce; h==0 half stores uint2.
__global__ __launch_bounds__(256) void prop_bf16_kernel(
    const uint2* __restrict__ hin2, uint2* __restrict__ hout2,
    const int* __restrict__ row_ptr, const unsigned* __restrict__ e_cw, int n)
{
    int wv = __builtin_amdgcn_readfirstlane(threadIdx.x >> 6);
    int node = blockIdx.x * 4 + wv;
    if (node >= n) return;
    const int lane = threadIdx.x & 63;
    const int h = lane >> 5;       // edge parity within pair
    const int s = lane & 31;       // 8B segment (features 4s..4s+3)
    int rs = row_ptr[node];
    int re = row_ptr[node + 1];

    float a0 = 0.f, a1 = 0.f, a2 = 0.f, a3 = 0.f;

    for (int j = rs; j < re; j += 24) {
        uint2 vv[12]; float wv2[12];
        #pragma unroll
        for (int u = 0; u < 12; ++u) {
            int i0 = j + 2 * u;
            unsigned cw0 = (i0     < re) ? e_cw[i0]     : 0u;   // uniform -> s_load/s_cselect
            unsigned cw1 = (i0 + 1 < re) ? e_cw[i0 + 1] : 0u;
            unsigned cw = h ? cw1 : cw0;
            wv2[u] = f16w(cw);
            vv[u] = hin2[(size_t)(cw & 0xffffu) * 32 + s];
        }
        #pragma unroll
        for (int u = 0; u < 12; ++u) {
            float w = wv2[u];
            a0 += w * blo(vv[u].x);  a1 += w * bhi(vv[u].x);
            a2 += w * blo(vv[u].y);  a3 += w * bhi(vv[u].y);
        }
    }
    // combine the two halves (both hold the same features for this node)
    a0 += __shfl_xor(a0, 32);
    a1 += __shfl_xor(a1, 32);
    a2 += __shfl_xor(a2, 32);
    a3 += __shfl_xor(a3, 32);

    if (h == 0) {
        uint2 o;
        o.x = pack_bf16(a0, a1);
        o.y = pack_bf16(a2, a3);
        hout2[(size_t)node * 32 + s] = o;
    }
}

// ---------------- fused: prop2 (t2 = L_hat @ t1, per-wave -> LDS) + 3-way MFMA GEMM + bias + ReLU ----
// Block = 256 thr = 4 waves = 64 rows; each wave owns rows wave*16..wave*16+15:
//   phase 1: gather t2 for its own 16 nodes into a 16 KB XOR-swizzled LDS tile
//            (LDS is the lane-layout transpose: gather layout -> MFMA A-frag layout)
//   phase 2: acc = X0@W0' + X1@W1 + X2s@W2' with B-fragments read directly from
//            global (32 KB/seg -> L1-resident), no Ws staging, no per-seg barriers.
__global__ __launch_bounds__(256) void gemm_fused_kernel(
    const unsigned short* __restrict__ X0, const unsigned short* __restrict__ X1,
    const unsigned short* __restrict__ Wt, const float* __restrict__ bias,
    void* __restrict__ out, const int* __restrict__ row_ptr,
    const unsigned* __restrict__ e_cw, int n, int out_bf16)
{
    __shared__ unsigned short X2s[64 * DFEAT];   // 16 KB, rows XOR-swizzled by (row&7)<<4

    const int t    = threadIdx.x;
    const int wave = __builtin_amdgcn_readfirstlane(t >> 6);
    const int lane = t & 63;
    const int row_base = blockIdx.x * 64;

    // ---------- phase 1: t2 rows for this wave's 16 nodes -> LDS ----------
    {
        const uint2* __restrict__ x1_2 = (const uint2*)X1;
        const int h = lane >> 5;
        const int s = lane & 31;
        for (int i = 0; i < 16; ++i) {
            const int lrow = wave * 16 + i;
            const int node = row_base + lrow;
            if (node >= n) break;                // uniform per wave
            int rs = row_ptr[node];
            int re = row_ptr[node + 1];
            float a0 = 0.f, a1 = 0.f, a2 = 0.f, a3 = 0.f;
            for (int j = rs; j < re; j += 24) {
                uint2 vv[12]; float wv2[12];
                #pragma unroll
                for (int u = 0; u < 12; ++u) {
                    int i0 = j + 2 * u;
                    unsigned cw0 = (i0     < re) ? e_cw[i0]     : 0u;
                    unsigned cw1 = (i0 + 1 < re) ? e_cw[i0 + 1] : 0u;
                    unsigned cw = h ? cw1 : cw0;
                    wv2[u] = f16w(cw);
                    vv[u] = x1_2[(size_t)(cw & 0xffffu) * 32 + s];
                }
                #pragma unroll
                for (int u = 0; u < 12; ++u) {
                    float w = wv2[u];
                    a0 += w * blo(vv[u].x);  a1 += w * bhi(vv[u].x);
                    a2 += w * blo(vv[u].y);  a3 += w * bhi(vv[u].y);
                }
            }
            a0 += __shfl_xor(a0, 32);
            a1 += __shfl_xor(a1, 32);
            a2 += __shfl_xor(a2, 32);
            a3 += __shfl_xor(a3, 32);
            if (h == 0) {
                uint2 o;
                o.x = pack_bf16(a0, a1);
                o.y = pack_bf16(a2, a3);
                unsigned byte = (unsigned)(lrow * 256 + s * 8);
                byte ^= (unsigned)((lrow & 7) << 4);      // bank swizzle, keeps 8B align
                *(uint2*)((char*)X2s + byte) = o;
            }
        }
    }
    __syncthreads();   // safety only: each wave reads back its own rows

    // ---------- phase 2: 3-seg MFMA GEMM ----------
    const int quad = lane >> 4;
    const int l16  = lane & 15;
    int r0 = row_base + wave * 16 + l16;
    if (r0 >= n) r0 = n - 1;

    f32x4 acc[8];
    #pragma unroll
    for (int c = 0; c < 8; ++c) acc[c] = (f32x4){0.f, 0.f, 0.f, 0.f};

    #pragma unroll
    for (int seg = 0; seg < 3; ++seg) {
        bf16x8 a[4];
        if (seg < 2) {
            const unsigned short* Ap =
                ((seg == 0) ? X0 : X1) + (size_t)r0 * DFEAT + quad * 8;
            #pragma unroll
            for (int kk = 0; kk < 4; ++kk) a[kk] = *(const bf16x8*)(Ap + kk * 32);
        } else {
            const int lr = wave * 16 + l16;
            #pragma unroll
            for (int kk = 0; kk < 4; ++kk) {
                unsigned byte = (unsigned)(lr * 256 + kk * 64 + quad * 16);
                byte ^= (unsigned)((lr & 7) << 4);        // same involution as store
                a[kk] = *(const bf16x8*)((const char*)X2s + byte);
            }
        }
        const unsigned short* Bp = Wt + (seg << 14) + l16 * DFEAT + quad * 8;
        #pragma unroll
        for (int c = 0; c < 8; ++c) {
            #pragma unroll
            for (int kk = 0; kk < 4; ++kk) {
                bf16x8 b = *(const bf16x8*)(Bp + c * 16 * DFEAT + kk * 32);
                acc[c] = __builtin_amdgcn_mfma_f32_16x16x32_bf16(a[kk], b, acc[c], 0, 0, 0);
            }
        }
    }

    // epilogue: C/D layout col = lane&15, row = quad*4 + reg
    const int orow0 = row_base + wave * 16 + quad * 4;
    #pragma unroll
    for (int c = 0; c < 8; ++c) {
        const int col = c * 16 + l16;
        const float bv = bias[col];
        #pragma unroll
        for (int r = 0; r < 4; ++r) {
            const int orow = orow0 + r;
            if (orow < n) {
                float v = fmaxf(acc[c][r] + bv, 0.f);
                if (out_bf16)
                    ((unsigned short*)out)[(size_t)orow * DFEAT + col] = (unsigned short)bf16r(v);
                else
                    ((float*)out)[(size_t)orow * DFEAT + col] = v;
            }
        }
    }
}

extern "C" void kernel_launch(void* const* d_in, const int* in_sizes, int n_in,
                              void* d_out, int out_size, void* d_ws, size_t ws_size,
                              hipStream_t stream) {
    const float* x  = (const float*)d_in[0];
    const int*   ei = (const int*)d_in[1];
    const float* W1 = (const float*)d_in[2];
    const float* b1 = (const float*)d_in[3];
    const float* W2 = (const float*)d_in[4];
    const float* b2 = (const float*)d_in[5];
    const float* W3 = (const float*)d_in[6];
    const float* b3 = (const float*)d_in[7];

    const int N = in_sizes[0] / DFEAT;   // 50000
    const int E = in_sizes[1] / 2;       // 800000
    const int NPK = N * (DFEAT / 2);     // packed bf16x2 words per array
    const int NB = (N + 1023) / 1024;    // scan blocks

    // workspace layout
    unsigned* xb  = (unsigned*)d_ws;
    unsigned* t1b = xb  + NPK;
    unsigned* t2b = t1b + NPK;           // (kept in layout; unused after fusion)
    unsigned* ab  = t2b + NPK;
    unsigned short* wt = (unsigned short*)(ab + NPK);   // 3 layers * 3*128*128
    int*   deg8    = (int*)(wt + 3 * 3 * DFEAT * DFEAT);
    int*   poff    = deg8 + 8 * N;
    int*   row_ptr = poff + 8 * N;
    float* dinv    = (float*)(row_ptr + (N + 2));
    unsigned* e_cw = (unsigned*)(dinv + N);
    int*   bsum    = (int*)(e_cw + E);

    const int WELEM = 3 * DFEAT * DFEAT;
    const int CONVT = NPK + 3 * WELEM;
    conv_kernel<<<(CONVT + 255) / 256, 256, 0, stream>>>(
        (const float2*)x, xb, NPK, W1, W2, W3, wt, deg8, N);
    deg_kernel<<<(E + 255) / 256, 256, 0, stream>>>(ei, deg8, E, N);
    scan1_kernel<<<NB, 1024, 0, stream>>>(deg8, poff, row_ptr, bsum, dinv, N);
    scan3_kernel<<<NB, 1024, 0, stream>>>(row_ptr, bsum, N);
    fill_kernel<<<(E + 255) / 256, 256, 0, stream>>>(ei, row_ptr, poff, dinv, e_cw, E, N);

    const float* bl[3] = {b1, b2, b3};
    const unsigned* hin = xb;
    const int prop_grid = (N + 3) / 4;
    const int fused_grid = (N + 63) / 64;
    for (int l = 0; l < 3; ++l) {
        // Tx1 = L_hat @ h
        prop_bf16_kernel<<<prop_grid, 256, 0, stream>>>(
            (const uint2*)hin, (uint2*)t1b, row_ptr, e_cw, N);
        // fused: P = L_hat @ Tx1 (in-kernel, LDS) ; out = relu(h@(W0-W2) + Tx1@W1 + P@(2W2) + b)
        void* hout = (l == 2) ? d_out : (void*)ab;
        gemm_fused_kernel<<<fused_grid, 256, 0, stream>>>(
            (const unsigned short*)hin, (const unsigned short*)t1b,
            wt + l * WELEM, bl[l], hout, row_ptr, e_cw, N, (l == 2) ? 0 : 1);
        hin = ab;
    }
}

// Round 2
// 465.869 us; speedup vs baseline: 1.0500x; 1.0500x over previous
//
#include <hip/hip_runtime.h>
#include <hip/hip_bf16.h>

#define DFEAT 128

typedef short bf16x8 __attribute__((ext_vector_type(8)));
typedef float f32x4  __attribute__((ext_vector_type(4)));
typedef unsigned short u16x8 __attribute__((ext_vector_type(8)));

__device__ __forceinline__ unsigned bf16r(float f) {
    unsigned u = __float_as_uint(f);
    u += 0x7fffu + ((u >> 16) & 1u);   // round-to-nearest-even
    return u >> 16;
}
__device__ __forceinline__ unsigned pack_bf16(float lo, float hi) {
    return bf16r(lo) | (bf16r(hi) << 16);
}
__device__ __forceinline__ float blo(unsigned v) { return __uint_as_float(v << 16); }
__device__ __forceinline__ float bhi(unsigned v) { return __uint_as_float(v & 0xffff0000u); }
__device__ __forceinline__ float f16w(unsigned cw) {
    unsigned short wb = (unsigned short)(cw >> 16);
    _Float16 hf; __builtin_memcpy(&hf, &wb, 2);
    return (float)hf;
}

// Chebyshev algebra folded into weights (fp32, at prep):
//   out = h@W0 + Tx1@W1 + (2P - h)@W2,  P = L_hat @ Tx1
//       = h@(W0 - W2) + Tx1@W1 + P@(2*W2)
// -> both props are identical pure gathers (no subtract, no alpha).

// ---------------- conv (FIRST): zero deg8 + x->bf16 pack + W->folded transposed bf16 ----------------
__global__ void conv_kernel(const float2* __restrict__ x, unsigned* __restrict__ xb, int npk,
                            const float* __restrict__ W1, const float* __restrict__ W2,
                            const float* __restrict__ W3, unsigned short* __restrict__ Wt,
                            int* __restrict__ deg8, int N) {
    int id = blockIdx.x * blockDim.x + threadIdx.x;
    int gstride = gridDim.x * blockDim.x;
    for (int i = id; i < 8 * N; i += gstride) deg8[i] = 0;
    if (id < npk) {
        float2 v = x[id];
        xb[id] = pack_bf16(v.x, v.y);
        return;
    }
    int id2 = id - npk;
    const int PER = 3 * DFEAT * DFEAT;
    if (id2 < 3 * PER) {
        int layer = id2 / PER;
        int rem = id2 - layer * PER;
        const float* W = (layer == 0) ? W1 : ((layer == 1) ? W2 : W3);
        int seg = rem >> 14;
        int k   = (rem >> 7) & 127;
        int nn  = rem & 127;
        float w = W[rem];
        if (seg == 0) w -= W[rem + 2 * DFEAT * DFEAT];   // W0' = W0 - W2
        else if (seg == 2) w *= 2.f;                      // W2' = 2*W2
        Wt[layer * PER + (seg << 14) + (nn << 7) + k] = (unsigned short)bf16r(w);
    }
}

// ---------------- degree count (XCD-privatized, fire-and-forget atomics) ----------------
__global__ void deg_kernel(const int* __restrict__ ei, int* __restrict__ deg8, int E, int N) {
    int e = blockIdx.x * blockDim.x + threadIdx.x;
    if (e < E) {
        int r = ei[e];
        int c = ei[E + e];
        if (r != c) atomicAdd(&deg8[(blockIdx.x & 7) * N + r], 1);
    }
}

// ---------------- scan stage 1: partition prefix -> poff, totals -> dinv, block scan ----------------
__global__ __launch_bounds__(1024) void scan1_kernel(const int* __restrict__ deg8,
                                                     int* __restrict__ poff,
                                                     int* __restrict__ row_ptr,
                                                     int* __restrict__ bsum,
                                                     float* __restrict__ dinv, int n) {
    __shared__ int wsums[16];
    int t = threadIdx.x;
    int idx = blockIdx.x * 1024 + t;
    int tot = 0;
    if (idx < n) {
        int run = 0;
        #pragma unroll
        for (int p = 0; p < 8; ++p) {
            int d = deg8[p * n + idx];
            poff[p * n + idx] = run;   // partition start within row; doubles as fill cursor
            run += d;
        }
        tot = run;
        dinv[idx] = (tot > 0) ? rsqrtf((float)tot) : 0.f;
    }
    int vi = tot;
    #pragma unroll
    for (int off = 1; off < 64; off <<= 1) {
        int x = __shfl_up(vi, off);
        if ((t & 63) >= off) vi += x;
    }
    if ((t & 63) == 63) wsums[t >> 6] = vi;
    __syncthreads();
    if (t < 16) {
        int s = wsums[t];
        int si = s;
        #pragma unroll
        for (int off = 1; off < 16; off <<= 1) {
            int x = __shfl_up(si, off);
            if (t >= off) si += x;
        }
        wsums[t] = si - s;
        if (t == 15) bsum[blockIdx.x] = si;   // block total
    }
    __syncthreads();
    if (idx < n) row_ptr[idx + 1] = wsums[t >> 6] + vi;
}

// ---------------- scan stage 2+3 merged: each block reduces its bsum prefix itself ----------------
__global__ __launch_bounds__(1024) void scan3_kernel(int* __restrict__ row_ptr,
                                                     const int* __restrict__ bsum, int n) {
    __shared__ int soff;
    int t = threadIdx.x;
    if (t < 64) {
        int v = 0;
        for (int k = t; k < (int)blockIdx.x; k += 64) v += bsum[k];
        #pragma unroll
        for (int off = 32; off > 0; off >>= 1) v += __shfl_down(v, off);
        if (t == 0) soff = v;
    }
    __syncthreads();
    int idx = blockIdx.x * 1024 + t;
    if (idx == 0) row_ptr[0] = 0;
    if (idx < n) row_ptr[idx + 1] += soff;
}

// ---------------- CSR fill: packed (col:u16 | w:f16); poff doubles as cursor ----------------
__global__ void fill_kernel(const int* __restrict__ ei, const int* __restrict__ row_ptr,
                            int* __restrict__ poff, const float* __restrict__ dinv,
                            unsigned* __restrict__ e_cw, int E, int N) {
    int e = blockIdx.x * blockDim.x + threadIdx.x;
    if (e < E) {
        int r = ei[e];
        int c = ei[E + e];
        if (r != c) {
            int p = blockIdx.x & 7;
            int k = atomicAdd(&poff[p * N + r], 1);   // cursor = partition base + count
            int pos = row_ptr[r] + k;
            float w = -dinv[r] * dinv[c];
            _Float16 hf = (_Float16)w;
            unsigned short wb;
            __builtin_memcpy(&wb, &hf, 2);
            e_cw[pos] = (unsigned)c | ((unsigned)wb << 16);
        }
    }
}

// ---------------- sparse prop (pure gather: hout = L_hat @ hin) ----------------
// 1 wave per node; 2 edges per wave via half-wave split: lane = (h = lane>>5
// edge parity, s = lane&31 8B segment -> features 4s..4s+3). Metadata via
// wave-uniform scalar loads + cndmask select; 12-pair phases -> 6 KB in
// flight per wave. Cross-half shfl_xor reduce; h==0 half stores uint2.
__global__ __launch_bounds__(256) void prop_bf16_kernel(
    const uint2* __restrict__ hin2, uint2* __restrict__ hout2,
    const int* __restrict__ row_ptr, const unsigned* __restrict__ e_cw, int n)
{
    int wv = __builtin_amdgcn_readfirstlane(threadIdx.x >> 6);
    int node = blockIdx.x * 4 + wv;
    if (node >= n) return;
    const int lane = threadIdx.x & 63;
    const int h = lane >> 5;       // edge parity within pair
    const int s = lane & 31;       // 8B segment (features 4s..4s+3)
    int rs = row_ptr[node];
    int re = row_ptr[node + 1];

    float a0 = 0.f, a1 = 0.f, a2 = 0.f, a3 = 0.f;

    for (int j = rs; j < re; j += 24) {
        uint2 vv[12]; float wv2[12];
        #pragma unroll
        for (int u = 0; u < 12; ++u) {
            int i0 = j + 2 * u;
            unsigned cw0 = (i0     < re) ? e_cw[i0]     : 0u;   // uniform -> s_load/s_cselect
            unsigned cw1 = (i0 + 1 < re) ? e_cw[i0 + 1] : 0u;
            unsigned cw = h ? cw1 : cw0;
            wv2[u] = f16w(cw);
            vv[u] = hin2[(size_t)(cw & 0xffffu) * 32 + s];
        }
        #pragma unroll
        for (int u = 0; u < 12; ++u) {
            float w = wv2[u];
            a0 += w * blo(vv[u].x);  a1 += w * bhi(vv[u].x);
            a2 += w * blo(vv[u].y);  a3 += w * bhi(vv[u].y);
        }
    }
    // combine the two halves (both hold the same features for this node)
    a0 += __shfl_xor(a0, 32);
    a1 += __shfl_xor(a1, 32);
    a2 += __shfl_xor(a2, 32);
    a3 += __shfl_xor(a3, 32);

    if (h == 0) {
        uint2 o;
        o.x = pack_bf16(a0, a1);
        o.y = pack_bf16(a2, a3);
        hout2[(size_t)node * 32 + s] = o;
    }
}

// ---------------- fused: prop2 (t2 = L_hat @ t1, per-wave -> LDS) + 3-way MFMA GEMM + bias + ReLU ----
// Block = 256 thr = 4 waves = 16 rows (grid 3125 -> 32 waves/CU, matches the
// standalone prop's latency hiding). Phase 1: wave w gathers 4 nodes
// (rows 4w..4w+3) into a 4 KB XOR-swizzled LDS tile. Phase 2: waves split the
// COLUMN dim: wave w computes out cols 32w..32w+31 for all 16 rows (2 c-frags,
// 24 MFMA). B-frags read directly from global (L2-resident Wt), no staging.
__global__ __launch_bounds__(256) void gemm_fused_kernel(
    const unsigned short* __restrict__ X0, const unsigned short* __restrict__ X1,
    const unsigned short* __restrict__ Wt, const float* __restrict__ bias,
    void* __restrict__ out, const int* __restrict__ row_ptr,
    const unsigned* __restrict__ e_cw, int n, int out_bf16)
{
    __shared__ unsigned short X2s[16 * DFEAT];   // 4 KB, rows XOR-swizzled by (row&7)<<4

    const int t    = threadIdx.x;
    const int wave = __builtin_amdgcn_readfirstlane(t >> 6);
    const int lane = t & 63;
    const int row_base = blockIdx.x * 16;

    // ---------- phase 1: t2 rows (4 per wave) -> LDS ----------
    {
        const uint2* __restrict__ x1_2 = (const uint2*)X1;
        const int h = lane >> 5;
        const int s = lane & 31;
        #pragma unroll
        for (int i = 0; i < 4; ++i) {
            const int lrow = wave * 4 + i;
            const int node = row_base + lrow;
            float a0 = 0.f, a1 = 0.f, a2 = 0.f, a3 = 0.f;
            if (node < n) {                       // uniform per wave
                int rs = row_ptr[node];
                int re = row_ptr[node + 1];
                for (int j = rs; j < re; j += 24) {
                    uint2 vv[12]; float wv2[12];
                    #pragma unroll
                    for (int u = 0; u < 12; ++u) {
                        int i0 = j + 2 * u;
                        unsigned cw0 = (i0     < re) ? e_cw[i0]     : 0u;
                        unsigned cw1 = (i0 + 1 < re) ? e_cw[i0 + 1] : 0u;
                        unsigned cw = h ? cw1 : cw0;
                        wv2[u] = f16w(cw);
                        vv[u] = x1_2[(size_t)(cw & 0xffffu) * 32 + s];
                    }
                    #pragma unroll
                    for (int u = 0; u < 12; ++u) {
                        float w = wv2[u];
                        a0 += w * blo(vv[u].x);  a1 += w * bhi(vv[u].x);
                        a2 += w * blo(vv[u].y);  a3 += w * bhi(vv[u].y);
                    }
                }
                a0 += __shfl_xor(a0, 32);
                a1 += __shfl_xor(a1, 32);
                a2 += __shfl_xor(a2, 32);
                a3 += __shfl_xor(a3, 32);
            }
            if (h == 0) {
                uint2 o;
                o.x = pack_bf16(a0, a1);
                o.y = pack_bf16(a2, a3);
                unsigned byte = (unsigned)(lrow * 256 + s * 8);
                byte ^= (unsigned)((lrow & 7) << 4);      // bank swizzle, keeps 8B align
                *(uint2*)((char*)X2s + byte) = o;
            }
        }
    }
    __syncthreads();

    // ---------- phase 2: 3-seg MFMA GEMM, wave w -> cols 32w..32w+31 ----------
    const int quad = lane >> 4;
    const int l16  = lane & 15;
    int r0 = row_base + l16;
    if (r0 >= n) r0 = n - 1;

    f32x4 acc[2];
    acc[0] = (f32x4){0.f, 0.f, 0.f, 0.f};
    acc[1] = (f32x4){0.f, 0.f, 0.f, 0.f};

    #pragma unroll
    for (int seg = 0; seg < 3; ++seg) {
        bf16x8 a[4];
        if (seg < 2) {
            const unsigned short* Ap =
                ((seg == 0) ? X0 : X1) + (size_t)r0 * DFEAT + quad * 8;
            #pragma unroll
            for (int kk = 0; kk < 4; ++kk) a[kk] = *(const bf16x8*)(Ap + kk * 32);
        } else {
            #pragma unroll
            for (int kk = 0; kk < 4; ++kk) {
                unsigned byte = (unsigned)(l16 * 256 + kk * 64 + quad * 16);
                byte ^= (unsigned)((l16 & 7) << 4);        // same involution as store
                a[kk] = *(const bf16x8*)((const char*)X2s + byte);
            }
        }
        #pragma unroll
        for (int c2 = 0; c2 < 2; ++c2) {
            const int c = wave * 2 + c2;
            const unsigned short* Bp = Wt + (seg << 14) + (c * 16 + l16) * DFEAT + quad * 8;
            #pragma unroll
            for (int kk = 0; kk < 4; ++kk) {
                bf16x8 b = *(const bf16x8*)(Bp + kk * 32);
                acc[c2] = __builtin_amdgcn_mfma_f32_16x16x32_bf16(a[kk], b, acc[c2], 0, 0, 0);
            }
        }
    }

    // epilogue: C/D layout col = lane&15, row = quad*4 + reg
    #pragma unroll
    for (int c2 = 0; c2 < 2; ++c2) {
        const int c = wave * 2 + c2;
        const int col = c * 16 + l16;
        const float bv = bias[col];
        #pragma unroll
        for (int r = 0; r < 4; ++r) {
            const int orow = row_base + quad * 4 + r;
            if (orow < n) {
                float v = fmaxf(acc[c2][r] + bv, 0.f);
                if (out_bf16)
                    ((unsigned short*)out)[(size_t)orow * DFEAT + col] = (unsigned short)bf16r(v);
                else
                    ((float*)out)[(size_t)orow * DFEAT + col] = v;
            }
        }
    }
}

extern "C" void kernel_launch(void* const* d_in, const int* in_sizes, int n_in,
                              void* d_out, int out_size, void* d_ws, size_t ws_size,
                              hipStream_t stream) {
    const float* x  = (const float*)d_in[0];
    const int*   ei = (const int*)d_in[1];
    const float* W1 = (const float*)d_in[2];
    const float* b1 = (const float*)d_in[3];
    const float* W2 = (const float*)d_in[4];
    const float* b2 = (const float*)d_in[5];
    const float* W3 = (const float*)d_in[6];
    const float* b3 = (const float*)d_in[7];

    const int N = in_sizes[0] / DFEAT;   // 50000
    const int E = in_sizes[1] / 2;       // 800000
    const int NPK = N * (DFEAT / 2);     // packed bf16x2 words per array
    const int NB = (N + 1023) / 1024;    // scan blocks

    // workspace layout
    unsigned* xb  = (unsigned*)d_ws;
    unsigned* t1b = xb  + NPK;
    unsigned* t2b = t1b + NPK;           // (kept in layout; unused after fusion)
    unsigned* ab  = t2b + NPK;
    unsigned short* wt = (unsigned short*)(ab + NPK);   // 3 layers * 3*128*128
    int*   deg8    = (int*)(wt + 3 * 3 * DFEAT * DFEAT);
    int*   poff    = deg8 + 8 * N;
    int*   row_ptr = poff + 8 * N;
    float* dinv    = (float*)(row_ptr + (N + 2));
    unsigned* e_cw = (unsigned*)(dinv + N);
    int*   bsum    = (int*)(e_cw + E);

    const int WELEM = 3 * DFEAT * DFEAT;
    const int CONVT = NPK + 3 * WELEM;
    conv_kernel<<<(CONVT + 255) / 256, 256, 0, stream>>>(
        (const float2*)x, xb, NPK, W1, W2, W3, wt, deg8, N);
    deg_kernel<<<(E + 255) / 256, 256, 0, stream>>>(ei, deg8, E, N);
    scan1_kernel<<<NB, 1024, 0, stream>>>(deg8, poff, row_ptr, bsum, dinv, N);
    scan3_kernel<<<NB, 1024, 0, stream>>>(row_ptr, bsum, N);
    fill_kernel<<<(E + 255) / 256, 256, 0, stream>>>(ei, row_ptr, poff, dinv, e_cw, E, N);

    const float* bl[3] = {b1, b2, b3};
    const unsigned* hin = xb;
    const int prop_grid = (N + 3) / 4;
    const int fused_grid = (N + 15) / 16;
    for (int l = 0; l < 3; ++l) {
        // Tx1 = L_hat @ h
        prop_bf16_kernel<<<prop_grid, 256, 0, stream>>>(
            (const uint2*)hin, (uint2*)t1b, row_ptr, e_cw, N);
        // fused: P = L_hat @ Tx1 (in-kernel, LDS) ; out = relu(h@(W0-W2) + Tx1@W1 + P@(2W2) + b)
        void* hout = (l == 2) ? d_out : (void*)ab;
        gemm_fused_kernel<<<fused_grid, 256, 0, stream>>>(
            (const unsigned short*)hin, (const unsigned short*)t1b,
            wt + l * WELEM, bl[l], hout, row_ptr, e_cw, N, (l == 2) ? 0 : 1);
        hin = ab;
    }
}

// Round 3
// 419.749 us; speedup vs baseline: 1.1654x; 1.1099x over previous
//
#include <hip/hip_runtime.h>
#include <hip/hip_bf16.h>

#define DFEAT 128

typedef short bf16x8 __attribute__((ext_vector_type(8)));
typedef float f32x4  __attribute__((ext_vector_type(4)));
typedef unsigned short u16x8 __attribute__((ext_vector_type(8)));

__device__ __forceinline__ unsigned bf16r(float f) {
    unsigned u = __float_as_uint(f);
    u += 0x7fffu + ((u >> 16) & 1u);   // round-to-nearest-even
    return u >> 16;
}
__device__ __forceinline__ unsigned pack_bf16(float lo, float hi) {
    return bf16r(lo) | (bf16r(hi) << 16);
}
__device__ __forceinline__ float blo(unsigned v) { return __uint_as_float(v << 16); }
__device__ __forceinline__ float bhi(unsigned v) { return __uint_as_float(v & 0xffff0000u); }
__device__ __forceinline__ float f16w(unsigned cw) {
    unsigned short wb = (unsigned short)(cw >> 16);
    _Float16 hf; __builtin_memcpy(&hf, &wb, 2);
    return (float)hf;
}

// Chebyshev algebra folded into weights (fp32, at prep):
//   out = h@W0 + Tx1@W1 + (2P - h)@W2,  P = L_hat @ Tx1
//       = h@(W0 - W2) + Tx1@W1 + P@(2*W2)
// -> both props are identical pure gathers (no subtract, no alpha).

// ---------------- conv (FIRST): zero deg8 + x->bf16 pack + W->folded transposed bf16 ----------------
__global__ void conv_kernel(const float2* __restrict__ x, unsigned* __restrict__ xb, int npk,
                            const float* __restrict__ W1, const float* __restrict__ W2,
                            const float* __restrict__ W3, unsigned short* __restrict__ Wt,
                            int* __restrict__ deg8, int N) {
    int id = blockIdx.x * blockDim.x + threadIdx.x;
    int gstride = gridDim.x * blockDim.x;
    for (int i = id; i < 8 * N; i += gstride) deg8[i] = 0;
    if (id < npk) {
        float2 v = x[id];
        xb[id] = pack_bf16(v.x, v.y);
        return;
    }
    int id2 = id - npk;
    const int PER = 3 * DFEAT * DFEAT;
    if (id2 < 3 * PER) {
        int layer = id2 / PER;
        int rem = id2 - layer * PER;
        const float* W = (layer == 0) ? W1 : ((layer == 1) ? W2 : W3);
        int seg = rem >> 14;
        int k   = (rem >> 7) & 127;
        int nn  = rem & 127;
        float w = W[rem];
        if (seg == 0) w -= W[rem + 2 * DFEAT * DFEAT];   // W0' = W0 - W2
        else if (seg == 2) w *= 2.f;                      // W2' = 2*W2
        Wt[layer * PER + (seg << 14) + (nn << 7) + k] = (unsigned short)bf16r(w);
    }
}

// ---------------- degree count (XCD-privatized, fire-and-forget atomics) ----------------
__global__ void deg_kernel(const int* __restrict__ ei, int* __restrict__ deg8, int E, int N) {
    int e = blockIdx.x * blockDim.x + threadIdx.x;
    if (e < E) {
        int r = ei[e];
        int c = ei[E + e];
        if (r != c) atomicAdd(&deg8[(blockIdx.x & 7) * N + r], 1);
    }
}

// ---------------- scan stage 1: partition prefix -> poff, totals -> dinv, block scan ----------------
__global__ __launch_bounds__(1024) void scan1_kernel(const int* __restrict__ deg8,
                                                     int* __restrict__ poff,
                                                     int* __restrict__ row_ptr,
                                                     int* __restrict__ bsum,
                                                     float* __restrict__ dinv, int n) {
    __shared__ int wsums[16];
    int t = threadIdx.x;
    int idx = blockIdx.x * 1024 + t;
    int tot = 0;
    if (idx < n) {
        int run = 0;
        #pragma unroll
        for (int p = 0; p < 8; ++p) {
            int d = deg8[p * n + idx];
            poff[p * n + idx] = run;   // partition start within row; doubles as fill cursor
            run += d;
        }
        tot = run;
        dinv[idx] = (tot > 0) ? rsqrtf((float)tot) : 0.f;
    }
    int vi = tot;
    #pragma unroll
    for (int off = 1; off < 64; off <<= 1) {
        int x = __shfl_up(vi, off);
        if ((t & 63) >= off) vi += x;
    }
    if ((t & 63) == 63) wsums[t >> 6] = vi;
    __syncthreads();
    if (t < 16) {
        int s = wsums[t];
        int si = s;
        #pragma unroll
        for (int off = 1; off < 16; off <<= 1) {
            int x = __shfl_up(si, off);
            if (t >= off) si += x;
        }
        wsums[t] = si - s;
        if (t == 15) bsum[blockIdx.x] = si;   // block total
    }
    __syncthreads();
    if (idx < n) row_ptr[idx + 1] = wsums[t >> 6] + vi;
}

// ---------------- scan stage 2+3 merged: each block reduces its bsum prefix itself ----------------
__global__ __launch_bounds__(1024) void scan3_kernel(int* __restrict__ row_ptr,
                                                     const int* __restrict__ bsum, int n) {
    __shared__ int soff;
    int t = threadIdx.x;
    if (t < 64) {
        int v = 0;
        for (int k = t; k < (int)blockIdx.x; k += 64) v += bsum[k];
        #pragma unroll
        for (int off = 32; off > 0; off >>= 1) v += __shfl_down(v, off);
        if (t == 0) soff = v;
    }
    __syncthreads();
    int idx = blockIdx.x * 1024 + t;
    if (idx == 0) row_ptr[0] = 0;
    if (idx < n) row_ptr[idx + 1] += soff;
}

// ---------------- CSR fill: packed (col:u16 | w:f16); poff doubles as cursor ----------------
__global__ void fill_kernel(const int* __restrict__ ei, const int* __restrict__ row_ptr,
                            int* __restrict__ poff, const float* __restrict__ dinv,
                            unsigned* __restrict__ e_cw, int E, int N) {
    int e = blockIdx.x * blockDim.x + threadIdx.x;
    if (e < E) {
        int r = ei[e];
        int c = ei[E + e];
        if (r != c) {
            int p = blockIdx.x & 7;
            int k = atomicAdd(&poff[p * N + r], 1);   // cursor = partition base + count
            int pos = row_ptr[r] + k;
            float w = -dinv[r] * dinv[c];
            _Float16 hf = (_Float16)w;
            unsigned short wb;
            __builtin_memcpy(&wb, &hf, 2);
            e_cw[pos] = (unsigned)c | ((unsigned)wb << 16);
        }
    }
}

// ---------------- sparse prop (pure gather: hout = L_hat @ hin) ----------------
// 2 nodes per wave, issued CONCURRENTLY (latency-bound fix: per-node in-flight
// edges is capped by deg~16; doubling nodes/wave doubles in-flight per wave).
// Per node: 2 edges via half-wave split (h = lane>>5 edge parity, s = lane&31
// 8B segment -> features 4s..4s+3), 12-pair phases. Issue A-loads, B-loads,
// then compute A (overlaps B flight), compute B. CSR adjacency: rsB = reA.
__global__ __launch_bounds__(256) void prop_bf16_kernel(
    const uint2* __restrict__ hin2, uint2* __restrict__ hout2,
    const int* __restrict__ row_ptr, const unsigned* __restrict__ e_cw, int n)
{
    int wv = __builtin_amdgcn_readfirstlane(threadIdx.x >> 6);
    int nodeA = blockIdx.x * 8 + wv * 2;
    if (nodeA >= n) return;
    const int nodeB = nodeA + 1;
    const bool hasB = nodeB < n;
    const int lane = threadIdx.x & 63;
    const int h = lane >> 5;       // edge parity within pair
    const int s = lane & 31;       // 8B segment (features 4s..4s+3)

    int rsA = row_ptr[nodeA];
    int reA = row_ptr[nodeA + 1];
    int reB = hasB ? row_ptr[nodeB + 1] : reA;   // rsB == reA (CSR contiguity)

    float aA0 = 0.f, aA1 = 0.f, aA2 = 0.f, aA3 = 0.f;
    float aB0 = 0.f, aB1 = 0.f, aB2 = 0.f, aB3 = 0.f;

    int jA = rsA, jB = reA;
    while (jA < reA || jB < reB) {
        uint2 vA[12]; float wA[12];
        uint2 vB[12]; float wB[12];
        #pragma unroll
        for (int u = 0; u < 12; ++u) {
            int i0 = jA + 2 * u;
            unsigned cw0 = (i0     < reA) ? e_cw[i0]     : 0u;   // uniform -> s_load/s_cselect
            unsigned cw1 = (i0 + 1 < reA) ? e_cw[i0 + 1] : 0u;
            unsigned cw = h ? cw1 : cw0;
            wA[u] = f16w(cw);
            vA[u] = hin2[(size_t)(cw & 0xffffu) * 32 + s];
        }
        #pragma unroll
        for (int u = 0; u < 12; ++u) {
            int i0 = jB + 2 * u;
            unsigned cw0 = (i0     < reB) ? e_cw[i0]     : 0u;
            unsigned cw1 = (i0 + 1 < reB) ? e_cw[i0 + 1] : 0u;
            unsigned cw = h ? cw1 : cw0;
            wB[u] = f16w(cw);
            vB[u] = hin2[(size_t)(cw & 0xffffu) * 32 + s];
        }
        #pragma unroll
        for (int u = 0; u < 12; ++u) {
            float w = wA[u];
            aA0 += w * blo(vA[u].x);  aA1 += w * bhi(vA[u].x);
            aA2 += w * blo(vA[u].y);  aA3 += w * bhi(vA[u].y);
        }
        #pragma unroll
        for (int u = 0; u < 12; ++u) {
            float w = wB[u];
            aB0 += w * blo(vB[u].x);  aB1 += w * bhi(vB[u].x);
            aB2 += w * blo(vB[u].y);  aB3 += w * bhi(vB[u].y);
        }
        jA += 24; jB += 24;
    }

    // combine the two halves (both hold the same features for their node)
    aA0 += __shfl_xor(aA0, 32);
    aA1 += __shfl_xor(aA1, 32);
    aA2 += __shfl_xor(aA2, 32);
    aA3 += __shfl_xor(aA3, 32);
    aB0 += __shfl_xor(aB0, 32);
    aB1 += __shfl_xor(aB1, 32);
    aB2 += __shfl_xor(aB2, 32);
    aB3 += __shfl_xor(aB3, 32);

    if (h == 0) {
        uint2 o;
        o.x = pack_bf16(aA0, aA1);
        o.y = pack_bf16(aA2, aA3);
        hout2[(size_t)nodeA * 32 + s] = o;
        if (hasB) {
            uint2 o2;
            o2.x = pack_bf16(aB0, aB1);
            o2.y = pack_bf16(aB2, aB3);
            hout2[(size_t)nodeB * 32 + s] = o2;
        }
    }
}

// ---------------- fused 3-way MFMA GEMM + bias + ReLU ----------------
#define WPAD 136
__global__ __launch_bounds__(256) void gemm3_mfma_kernel(
    const unsigned short* __restrict__ X0, const unsigned short* __restrict__ X1,
    const unsigned short* __restrict__ X2,
    const unsigned short* __restrict__ Wt, const float* __restrict__ bias,
    void* __restrict__ out, int n, int out_bf16)
{
    __shared__ unsigned short Ws[DFEAT * WPAD];   // 34816 B
    const int t    = threadIdx.x;
    const int wave = t >> 6;
    const int lane = t & 63;
    const int quad = lane >> 4;
    const int l16  = lane & 15;

    const int row_base = blockIdx.x * 128 + wave * 32;
    int r0 = row_base + l16;       if (r0 >= n) r0 = n - 1;
    int r1 = row_base + 16 + l16;  if (r1 >= n) r1 = n - 1;

    const unsigned short* Xps[3] = {X0, X1, X2};

    f32x4 acc[2][8];
    #pragma unroll
    for (int tt = 0; tt < 2; ++tt)
        #pragma unroll
        for (int c = 0; c < 8; ++c) acc[tt][c] = (f32x4){0.f, 0.f, 0.f, 0.f};

    const int srow = t >> 1;            // staging: row 0..127
    const int shalf = (t & 1) * 64;     // half-row

    #pragma unroll
    for (int seg = 0; seg < 3; ++seg) {
        __syncthreads();   // previous seg fully consumed
        const unsigned short* Wp = Wt + (seg << 14);
        #pragma unroll
        for (int i = 0; i < 8; ++i) {
            *(u16x8*)&Ws[srow * WPAD + shalf + i * 8] =
                *(const u16x8*)&Wp[srow * DFEAT + shalf + i * 8];
        }
        __syncthreads();
        const unsigned short* A0 = Xps[seg] + (size_t)r0 * DFEAT;
        const unsigned short* A1 = Xps[seg] + (size_t)r1 * DFEAT;
        #pragma unroll
        for (int kk = 0; kk < 4; ++kk) {
            const int ko = kk * 32 + quad * 8;
            bf16x8 a0 = *(const bf16x8*)(A0 + ko);
            bf16x8 a1 = *(const bf16x8*)(A1 + ko);
            #pragma unroll
            for (int c = 0; c < 8; ++c) {
                bf16x8 b = *(const bf16x8*)&Ws[(c * 16 + l16) * WPAD + ko];
                acc[0][c] = __builtin_amdgcn_mfma_f32_16x16x32_bf16(a0, b, acc[0][c], 0, 0, 0);
                acc[1][c] = __builtin_amdgcn_mfma_f32_16x16x32_bf16(a1, b, acc[1][c], 0, 0, 0);
            }
        }
    }

    // C/D layout: col = lane&15, row = quad*4 + reg
    #pragma unroll
    for (int tt = 0; tt < 2; ++tt) {
        int orow0 = blockIdx.x * 128 + wave * 32 + tt * 16 + quad * 4;
        #pragma unroll
        for (int c = 0; c < 8; ++c) {
            int col = c * 16 + l16;
            float bv = bias[col];
            #pragma unroll
            for (int r = 0; r < 4; ++r) {
                int orow = orow0 + r;
                if (orow < n) {
                    float v = fmaxf(acc[tt][c][r] + bv, 0.f);
                    if (out_bf16)
                        ((unsigned short*)out)[(size_t)orow * DFEAT + col] = (unsigned short)bf16r(v);
                    else
                        ((float*)out)[(size_t)orow * DFEAT + col] = v;
                }
            }
        }
    }
}

extern "C" void kernel_launch(void* const* d_in, const int* in_sizes, int n_in,
                              void* d_out, int out_size, void* d_ws, size_t ws_size,
                              hipStream_t stream) {
    const float* x  = (const float*)d_in[0];
    const int*   ei = (const int*)d_in[1];
    const float* W1 = (const float*)d_in[2];
    const float* b1 = (const float*)d_in[3];
    const float* W2 = (const float*)d_in[4];
    const float* b2 = (const float*)d_in[5];
    const float* W3 = (const float*)d_in[6];
    const float* b3 = (const float*)d_in[7];

    const int N = in_sizes[0] / DFEAT;   // 50000
    const int E = in_sizes[1] / 2;       // 800000
    const int NPK = N * (DFEAT / 2);     // packed bf16x2 words per array
    const int NB = (N + 1023) / 1024;    // scan blocks

    // workspace layout
    unsigned* xb  = (unsigned*)d_ws;
    unsigned* t1b = xb  + NPK;
    unsigned* t2b = t1b + NPK;
    unsigned* ab  = t2b + NPK;
    unsigned short* wt = (unsigned short*)(ab + NPK);   // 3 layers * 3*128*128
    int*   deg8    = (int*)(wt + 3 * 3 * DFEAT * DFEAT);
    int*   poff    = deg8 + 8 * N;
    int*   row_ptr = poff + 8 * N;
    float* dinv    = (float*)(row_ptr + (N + 2));
    unsigned* e_cw = (unsigned*)(dinv + N);
    int*   bsum    = (int*)(e_cw + E);

    const int WELEM = 3 * DFEAT * DFEAT;
    const int CONVT = NPK + 3 * WELEM;
    conv_kernel<<<(CONVT + 255) / 256, 256, 0, stream>>>(
        (const float2*)x, xb, NPK, W1, W2, W3, wt, deg8, N);
    deg_kernel<<<(E + 255) / 256, 256, 0, stream>>>(ei, deg8, E, N);
    scan1_kernel<<<NB, 1024, 0, stream>>>(deg8, poff, row_ptr, bsum, dinv, N);
    scan3_kernel<<<NB, 1024, 0, stream>>>(row_ptr, bsum, N);
    fill_kernel<<<(E + 255) / 256, 256, 0, stream>>>(ei, row_ptr, poff, dinv, e_cw, E, N);

    const float* bl[3] = {b1, b2, b3};
    const unsigned* hin = xb;
    const int prop_grid = (N + 7) / 8;
    const int gemm_grid = (N + 127) / 128;
    for (int l = 0; l < 3; ++l) {
        // Tx1 = L_hat @ h
        prop_bf16_kernel<<<prop_grid, 256, 0, stream>>>(
            (const uint2*)hin, (uint2*)t1b, row_ptr, e_cw, N);
        // P = L_hat @ Tx1   (2P - h folded into weights)
        prop_bf16_kernel<<<prop_grid, 256, 0, stream>>>(
            (const uint2*)t1b, (uint2*)t2b, row_ptr, e_cw, N);
        // out = relu(h@(W0-W2) + Tx1@W1 + P@(2W2) + b)
        void* hout = (l == 2) ? d_out : (void*)ab;
        gemm3_mfma_kernel<<<gemm_grid, 256, 0, stream>>>(
            (const unsigned short*)hin, (const unsigned short*)t1b, (const unsigned short*)t2b,
            wt + l * WELEM, bl[l], hout, N, (l == 2) ? 0 : 1);
        hin = ab;
    }
}

// Round 4
// 388.361 us; speedup vs baseline: 1.2596x; 1.0808x over previous
//
#include <hip/hip_runtime.h>
#include <hip/hip_bf16.h>

#define DFEAT 128

typedef _Float16 h2 __attribute__((ext_vector_type(2)));
typedef _Float16 f16x8 __attribute__((ext_vector_type(8)));
typedef float f32x4  __attribute__((ext_vector_type(4)));
typedef unsigned short u16x8 __attribute__((ext_vector_type(8)));

__device__ __forceinline__ unsigned short f16b(float f) {
    _Float16 hf = (_Float16)f;
    unsigned short b; __builtin_memcpy(&b, &hf, 2);
    return b;
}
__device__ __forceinline__ unsigned pack_f16(float lo, float hi) {
    return (unsigned)f16b(lo) | ((unsigned)f16b(hi) << 16);
}
__device__ __forceinline__ float h2f(h2 v) { float f; __builtin_memcpy(&f, &v, 4); return f; }
__device__ __forceinline__ h2 f2h(float f) { h2 v; __builtin_memcpy(&v, &f, 4); return v; }

// Chebyshev algebra folded into weights (fp32, at prep):
//   out = h@W0 + Tx1@W1 + (2P - h)@W2,  P = L_hat @ Tx1
//       = h@(W0 - W2) + Tx1@W1 + P@(2*W2)
// -> both props are identical pure gathers (no subtract, no alpha).
// Whole pipeline is f16 (not bf16): more mantissa AND enables v_pk_fma_f16
// accumulation in prop (2 feats/instr, no unpack) -> ~1.6x less VALU/byte.

// ---------------- conv (FIRST): zero deg8 + x->f16 pack + W->folded transposed f16 ----------------
__global__ void conv_kernel(const float2* __restrict__ x, unsigned* __restrict__ xb, int npk,
                            const float* __restrict__ W1, const float* __restrict__ W2,
                            const float* __restrict__ W3, unsigned short* __restrict__ Wt,
                            int* __restrict__ deg8, int N) {
    int id = blockIdx.x * blockDim.x + threadIdx.x;
    int gstride = gridDim.x * blockDim.x;
    for (int i = id; i < 8 * N; i += gstride) deg8[i] = 0;
    if (id < npk) {
        float2 v = x[id];
        xb[id] = pack_f16(v.x, v.y);
        return;
    }
    int id2 = id - npk;
    const int PER = 3 * DFEAT * DFEAT;
    if (id2 < 3 * PER) {
        int layer = id2 / PER;
        int rem = id2 - layer * PER;
        const float* W = (layer == 0) ? W1 : ((layer == 1) ? W2 : W3);
        int seg = rem >> 14;
        int k   = (rem >> 7) & 127;
        int nn  = rem & 127;
        float w = W[rem];
        if (seg == 0) w -= W[rem + 2 * DFEAT * DFEAT];   // W0' = W0 - W2
        else if (seg == 2) w *= 2.f;                      // W2' = 2*W2
        Wt[layer * PER + (seg << 14) + (nn << 7) + k] = f16b(w);
    }
}

// ---------------- degree count (XCD-privatized, fire-and-forget atomics) ----------------
__global__ void deg_kernel(const int* __restrict__ ei, int* __restrict__ deg8, int E, int N) {
    int e = blockIdx.x * blockDim.x + threadIdx.x;
    if (e < E) {
        int r = ei[e];
        int c = ei[E + e];
        if (r != c) atomicAdd(&deg8[(blockIdx.x & 7) * N + r], 1);
    }
}

// ---------------- scan stage 1: partition prefix -> poff, totals -> dinv, block scan ----------------
__global__ __launch_bounds__(1024) void scan1_kernel(const int* __restrict__ deg8,
                                                     int* __restrict__ poff,
                                                     int* __restrict__ row_ptr,
                                                     int* __restrict__ bsum,
                                                     float* __restrict__ dinv, int n) {
    __shared__ int wsums[16];
    int t = threadIdx.x;
    int idx = blockIdx.x * 1024 + t;
    int tot = 0;
    if (idx < n) {
        int run = 0;
        #pragma unroll
        for (int p = 0; p < 8; ++p) {
            int d = deg8[p * n + idx];
            poff[p * n + idx] = run;   // partition start within row; doubles as fill cursor
            run += d;
        }
        tot = run;
        dinv[idx] = (tot > 0) ? rsqrtf((float)tot) : 0.f;
    }
    int vi = tot;
    #pragma unroll
    for (int off = 1; off < 64; off <<= 1) {
        int x = __shfl_up(vi, off);
        if ((t & 63) >= off) vi += x;
    }
    if ((t & 63) == 63) wsums[t >> 6] = vi;
    __syncthreads();
    if (t < 16) {
        int s = wsums[t];
        int si = s;
        #pragma unroll
        for (int off = 1; off < 16; off <<= 1) {
            int x = __shfl_up(si, off);
            if (t >= off) si += x;
        }
        wsums[t] = si - s;
        if (t == 15) bsum[blockIdx.x] = si;   // block total
    }
    __syncthreads();
    if (idx < n) row_ptr[idx + 1] = wsums[t >> 6] + vi;
}

// ---------------- scan stage 2+3 merged: each block reduces its bsum prefix itself ----------------
__global__ __launch_bounds__(1024) void scan3_kernel(int* __restrict__ row_ptr,
                                                     const int* __restrict__ bsum, int n) {
    __shared__ int soff;
    int t = threadIdx.x;
    if (t < 64) {
        int v = 0;
        for (int k = t; k < (int)blockIdx.x; k += 64) v += bsum[k];
        #pragma unroll
        for (int off = 32; off > 0; off >>= 1) v += __shfl_down(v, off);
        if (t == 0) soff = v;
    }
    __syncthreads();
    int idx = blockIdx.x * 1024 + t;
    if (idx == 0) row_ptr[0] = 0;
    if (idx < n) row_ptr[idx + 1] += soff;
}

// ---------------- CSR fill: packed (col:u16 | w:f16); poff doubles as cursor ----------------
__global__ void fill_kernel(const int* __restrict__ ei, const int* __restrict__ row_ptr,
                            int* __restrict__ poff, const float* __restrict__ dinv,
                            unsigned* __restrict__ e_cw, int E, int N) {
    int e = blockIdx.x * blockDim.x + threadIdx.x;
    if (e < E) {
        int r = ei[e];
        int c = ei[E + e];
        if (r != c) {
            int p = blockIdx.x & 7;
            int k = atomicAdd(&poff[p * N + r], 1);   // cursor = partition base + count
            int pos = row_ptr[r] + k;
            float w = -dinv[r] * dinv[c];
            e_cw[pos] = (unsigned)c | ((unsigned)f16b(w) << 16);
        }
    }
}

// ---------------- sparse prop (pure gather: hout = L_hat @ hin), f16 + pk_fma ----------------
// 1 wave per node; 2 edges per wave via half-wave split: lane = (h = lane>>5
// edge parity, s = lane&31 8B segment -> features 4s..4s+3). Metadata via
// wave-uniform scalar loads + cndmask select; 12-pair phases -> 6 KB in
// flight per wave. Accumulate with v_pk_fma_f16 (no unpack, 2 feats/instr).
// Cross-half shfl_xor reduce (pk_add); h==0 half stores uint2.
__global__ __launch_bounds__(256) void prop_f16_kernel(
    const uint2* __restrict__ hin2, uint2* __restrict__ hout2,
    const int* __restrict__ row_ptr, const unsigned* __restrict__ e_cw, int n)
{
    int wv = __builtin_amdgcn_readfirstlane(threadIdx.x >> 6);
    int node = blockIdx.x * 4 + wv;
    if (node >= n) return;
    const int lane = threadIdx.x & 63;
    const int h = lane >> 5;       // edge parity within pair
    const int s = lane & 31;       // 8B segment (features 4s..4s+3)
    int rs = row_ptr[node];
    int re = row_ptr[node + 1];

    h2 a01 = {(_Float16)0.f, (_Float16)0.f};
    h2 a23 = {(_Float16)0.f, (_Float16)0.f};

    for (int j = rs; j < re; j += 24) {
        uint2 vv[12]; unsigned ww[12];
        #pragma unroll
        for (int u = 0; u < 12; ++u) {
            int i0 = j + 2 * u;
            unsigned cw0 = (i0     < re) ? e_cw[i0]     : 0u;   // uniform -> s_load/s_cselect
            unsigned cw1 = (i0 + 1 < re) ? e_cw[i0 + 1] : 0u;
            unsigned cw = h ? cw1 : cw0;
            ww[u] = (cw & 0xffff0000u) | (cw >> 16);            // (w,w) packed f16 pair
            vv[u] = hin2[(size_t)(cw & 0xffffu) * 32 + s];
        }
        #pragma unroll
        for (int u = 0; u < 12; ++u) {
            h2 wp = f2h(__uint_as_float(ww[u]));
            a01 = f2h(__uint_as_float(vv[u].x)) * wp + a01;     // v_pk_fma_f16
            a23 = f2h(__uint_as_float(vv[u].y)) * wp + a23;
        }
    }
    // combine the two halves (both hold the same features for this node)
    a01 = a01 + f2h(__shfl_xor(h2f(a01), 32));
    a23 = a23 + f2h(__shfl_xor(h2f(a23), 32));

    if (h == 0) {
        uint2 o;
        o.x = __float_as_uint(h2f(a01));
        o.y = __float_as_uint(h2f(a23));
        hout2[(size_t)node * 32 + s] = o;
    }
}

// ---------------- fused 3-way MFMA GEMM (f16) + bias + ReLU ----------------
#define WPAD 136
__global__ __launch_bounds__(256) void gemm3_mfma_kernel(
    const unsigned short* __restrict__ X0, const unsigned short* __restrict__ X1,
    const unsigned short* __restrict__ X2,
    const unsigned short* __restrict__ Wt, const float* __restrict__ bias,
    void* __restrict__ out, int n, int out_f16)
{
    __shared__ unsigned short Ws[DFEAT * WPAD];   // 34816 B
    const int t    = threadIdx.x;
    const int wave = t >> 6;
    const int lane = t & 63;
    const int quad = lane >> 4;
    const int l16  = lane & 15;

    const int row_base = blockIdx.x * 128 + wave * 32;
    int r0 = row_base + l16;       if (r0 >= n) r0 = n - 1;
    int r1 = row_base + 16 + l16;  if (r1 >= n) r1 = n - 1;

    const unsigned short* Xps[3] = {X0, X1, X2};

    f32x4 acc[2][8];
    #pragma unroll
    for (int tt = 0; tt < 2; ++tt)
        #pragma unroll
        for (int c = 0; c < 8; ++c) acc[tt][c] = (f32x4){0.f, 0.f, 0.f, 0.f};

    const int srow = t >> 1;            // staging: row 0..127
    const int shalf = (t & 1) * 64;     // half-row

    #pragma unroll
    for (int seg = 0; seg < 3; ++seg) {
        __syncthreads();   // previous seg fully consumed
        const unsigned short* Wp = Wt + (seg << 14);
        #pragma unroll
        for (int i = 0; i < 8; ++i) {
            *(u16x8*)&Ws[srow * WPAD + shalf + i * 8] =
                *(const u16x8*)&Wp[srow * DFEAT + shalf + i * 8];
        }
        __syncthreads();
        const unsigned short* A0 = Xps[seg] + (size_t)r0 * DFEAT;
        const unsigned short* A1 = Xps[seg] + (size_t)r1 * DFEAT;
        #pragma unroll
        for (int kk = 0; kk < 4; ++kk) {
            const int ko = kk * 32 + quad * 8;
            f16x8 a0 = *(const f16x8*)(A0 + ko);
            f16x8 a1 = *(const f16x8*)(A1 + ko);
            #pragma unroll
            for (int c = 0; c < 8; ++c) {
                f16x8 b = *(const f16x8*)&Ws[(c * 16 + l16) * WPAD + ko];
                acc[0][c] = __builtin_amdgcn_mfma_f32_16x16x32_f16(a0, b, acc[0][c], 0, 0, 0);
                acc[1][c] = __builtin_amdgcn_mfma_f32_16x16x32_f16(a1, b, acc[1][c], 0, 0, 0);
            }
        }
    }

    // C/D layout: col = lane&15, row = quad*4 + reg
    #pragma unroll
    for (int tt = 0; tt < 2; ++tt) {
        int orow0 = blockIdx.x * 128 + wave * 32 + tt * 16 + quad * 4;
        #pragma unroll
        for (int c = 0; c < 8; ++c) {
            int col = c * 16 + l16;
            float bv = bias[col];
            #pragma unroll
            for (int r = 0; r < 4; ++r) {
                int orow = orow0 + r;
                if (orow < n) {
                    float v = fmaxf(acc[tt][c][r] + bv, 0.f);
                    if (out_f16)
                        ((unsigned short*)out)[(size_t)orow * DFEAT + col] = f16b(v);
                    else
                        ((float*)out)[(size_t)orow * DFEAT + col] = v;
                }
            }
        }
    }
}

extern "C" void kernel_launch(void* const* d_in, const int* in_sizes, int n_in,
                              void* d_out, int out_size, void* d_ws, size_t ws_size,
                              hipStream_t stream) {
    const float* x  = (const float*)d_in[0];
    const int*   ei = (const int*)d_in[1];
    const float* W1 = (const float*)d_in[2];
    const float* b1 = (const float*)d_in[3];
    const float* W2 = (const float*)d_in[4];
    const float* b2 = (const float*)d_in[5];
    const float* W3 = (const float*)d_in[6];
    const float* b3 = (const float*)d_in[7];

    const int N = in_sizes[0] / DFEAT;   // 50000
    const int E = in_sizes[1] / 2;       // 800000
    const int NPK = N * (DFEAT / 2);     // packed f16x2 words per array
    const int NB = (N + 1023) / 1024;    // scan blocks

    // workspace layout
    unsigned* xb  = (unsigned*)d_ws;
    unsigned* t1b = xb  + NPK;
    unsigned* t2b = t1b + NPK;
    unsigned* ab  = t2b + NPK;
    unsigned short* wt = (unsigned short*)(ab + NPK);   // 3 layers * 3*128*128
    int*   deg8    = (int*)(wt + 3 * 3 * DFEAT * DFEAT);
    int*   poff    = deg8 + 8 * N;
    int*   row_ptr = poff + 8 * N;
    float* dinv    = (float*)(row_ptr + (N + 2));
    unsigned* e_cw = (unsigned*)(dinv + N);
    int*   bsum    = (int*)(e_cw + E);

    const int WELEM = 3 * DFEAT * DFEAT;
    const int CONVT = NPK + 3 * WELEM;
    conv_kernel<<<(CONVT + 255) / 256, 256, 0, stream>>>(
        (const float2*)x, xb, NPK, W1, W2, W3, wt, deg8, N);
    deg_kernel<<<(E + 255) / 256, 256, 0, stream>>>(ei, deg8, E, N);
    scan1_kernel<<<NB, 1024, 0, stream>>>(deg8, poff, row_ptr, bsum, dinv, N);
    scan3_kernel<<<NB, 1024, 0, stream>>>(row_ptr, bsum, N);
    fill_kernel<<<(E + 255) / 256, 256, 0, stream>>>(ei, row_ptr, poff, dinv, e_cw, E, N);

    const float* bl[3] = {b1, b2, b3};
    const unsigned* hin = xb;
    const int prop_grid = (N + 3) / 4;
    const int gemm_grid = (N + 127) / 128;
    for (int l = 0; l < 3; ++l) {
        // Tx1 = L_hat @ h
        prop_f16_kernel<<<prop_grid, 256, 0, stream>>>(
            (const uint2*)hin, (uint2*)t1b, row_ptr, e_cw, N);
        // P = L_hat @ Tx1   (2P - h folded into weights)
        prop_f16_kernel<<<prop_grid, 256, 0, stream>>>(
            (const uint2*)t1b, (uint2*)t2b, row_ptr, e_cw, N);
        // out = relu(h@(W0-W2) + Tx1@W1 + P@(2W2) + b)
        void* hout = (l == 2) ? d_out : (void*)ab;
        gemm3_mfma_kernel<<<gemm_grid, 256, 0, stream>>>(
            (const unsigned short*)hin, (const unsigned short*)t1b, (const unsigned short*)t2b,
            wt + l * WELEM, bl[l], hout, N, (l == 2) ? 0 : 1);
        hin = ab;
    }
}